// Round 11
// baseline (142.503 us; speedup 1.0000x reference)
//
#include <hip/hip_runtime.h>

// BinaryTreeShConv on MI355X (gfx950).
// out[b,v,i] = relu(bias[i] + sum_{p,c,rn} W[i,c,rn] * K[b,v,p,rn] * sig[b, idx[b,v,p], c])
// B=8 V=4096 P=32 C=32 RN=32 OUT=32, CRN=1024.
//
// R10: persistent blocks + cross-tile prefetch + minimal prep.
//  - grid 1024 x 256 thr; each block processes 4 tiles of 8 bv (32 bv, ck
//    contiguous 128 KB). Tile t+1's ck f32x4 loads + idx s_loads issue DURING
//    tile t's compute -> ck stream never stalls (T14 issue-early/write-late).
//  - prep shrunk to Wf pack only (128 blocks); sig gathered directly as f32
//    + round-half-up (R0/R1 proved conversion-in-loop is free; R3/4 numerics).
//  - phase structure per tile = R9 (best, 38.8): stream -> A -> B -> reduce.

typedef __attribute__((ext_vector_type(8))) short bf16x8;
typedef __attribute__((ext_vector_type(4))) short short4v;
typedef __attribute__((ext_vector_type(16))) float f32x16;
typedef __attribute__((ext_vector_type(4))) float f32x4;

__device__ __forceinline__ unsigned short f2bf_rne(float f) {
    union { float f; unsigned int u; } x;
    x.f = f;
    unsigned int u = x.u;
    return (unsigned short)((u + 0x7fffu + ((u >> 16) & 1u)) >> 16);
}
__device__ __forceinline__ unsigned short f2bf_rh(float f) {  // round-half-up
    union { float f; unsigned int u; } x;
    x.f = f;
    return (unsigned short)((x.u + 0x8000u) >> 16);
}

// Wf[pair=2s+t][lane][j] = bf16(W[i=16t+(lane&15)][crn=32s+8*(lane>>4)+j])
__global__ __launch_bounds__(256) void prep_kernel(
        const float* __restrict__ W, unsigned short* __restrict__ Wf) {
    int tid = blockIdx.x * 256 + threadIdx.x;   // 0..32767
    int j = tid & 7;
    int l = (tid >> 3) & 63;
    int pair = tid >> 9;                        // s*2 + t
    int s = pair >> 1;
    int t = pair & 1;
    int i = 16 * t + (l & 15);
    int crn = 32 * s + 8 * (l >> 4) + j;
    Wf[tid] = f2bf_rne(W[i * 1024 + crn]);
}

__global__ __launch_bounds__(256, 4) void fused_kernel(
        const float* __restrict__ sig, const int* __restrict__ pidx,
        const float* __restrict__ ck, const unsigned short* __restrict__ Wf,
        const float* __restrict__ bias, float* __restrict__ out) {
    __shared__ __align__(16) unsigned short ckb[8 * 1024];   // 16,384 B [bv][p][rn]
    __shared__ __align__(16) unsigned short T_lds[8 * 1032]; // 16,512 B
    const int tid = threadIdx.x;
    const int l = tid & 63;
    const int g = l >> 5;
    const int cc = l & 31;
    const int wu = __builtin_amdgcn_readfirstlane(tid >> 6);  // wave 0..3 (SGPR)
    const int base_m = blockIdx.x * 32;       // 32 bv per block, same b
    const float* sgb = sig + (size_t)(base_m >> 12) * (4096 * 32);
    const f32x4* ckv = (const f32x4*)(ck + (size_t)base_m * 1024);

    // ---- prologue: issue tile-0 ck stream + idx scalar loads ----
    f32x4 st[8];
    #pragma unroll
    for (int i = 0; i < 8; ++i) st[i] = ckv[i * 256 + tid];
    int rows[64];                              // wave-uniform addr -> s_loads
    {
        const int* ip = pidx + ((size_t)base_m + 2 * wu) * 32;
        #pragma unroll
        for (int k = 0; k < 64; ++k) rows[k] = ip[k];
    }

    for (int it = 0; it < 4; ++it) {
        const int m0 = base_m + it * 8;

        // ---- gathers for this tile (sig L2-resident, f32 + rh-convert) ----
        unsigned short ga[32];
        #pragma unroll
        for (int q = 0; q < 2; ++q)
            #pragma unroll
            for (int h = 0; h < 2; ++h)
                #pragma unroll
                for (int j = 0; j < 8; ++j) {
                    const int row = rows[q * 32 + h * 16 + 8 * g + j];
                    ga[q * 16 + h * 8 + j] = f2bf_rh(sgb[row * 32 + cc]);
                }

        // ---- pack current ck tile into LDS (consumes st) ----
        #pragma unroll
        for (int i = 0; i < 8; ++i) {
            union { f32x4 f; unsigned int u[4]; } x;
            x.f = st[i];
            short4v v = { (short)(x.u[0] >> 16), (short)(x.u[1] >> 16),
                          (short)(x.u[2] >> 16), (short)(x.u[3] >> 16) };
            *(short4v*)(ckb + (i * 256 + tid) * 4) = v;
        }

        // ---- issue NEXT tile's ck stream + idx (hide under phases A/B) ----
        if (it < 3) {
            #pragma unroll
            for (int i = 0; i < 8; ++i)
                st[i] = ckv[(it + 1) * 2048 + i * 256 + tid];
            const int* ip = pidx + ((size_t)m0 + 8 + 2 * wu) * 32;
            #pragma unroll
            for (int k = 0; k < 64; ++k) rows[k] = ip[k];
        }
        __syncthreads();

        // ---- Phase A: stage-A MFMA; wave wu owns bv_local 2wu, 2wu+1 ----
        #pragma unroll
        for (int q = 0; q < 2; ++q) {
            const unsigned short* ct = ckb + (2 * wu + q) * 1024;  // [32p][32rn]
            f32x16 acc = {};
            #pragma unroll
            for (int h = 0; h < 2; ++h) {
                bf16x8 af, bfr;
                #pragma unroll
                for (int j = 0; j < 8; ++j) {
                    const int p = h * 16 + 8 * g + j;
                    af[j]  = (short)ga[q * 16 + h * 8 + j];
                    bfr[j] = (short)ct[p * 32 + cc];
                }
                acc = __builtin_amdgcn_mfma_f32_32x32x16_bf16(af, bfr, acc, 0, 0, 0);
            }
            // D map (verified): col=cc, row=(r&3)+8*(r>>2)+4*g ; T[c][rn] bf16
            unsigned short* trow = T_lds + (2 * wu + q) * 1032 + cc + g * 128;
            #pragma unroll
            for (int r = 0; r < 16; ++r)
                trow[((r & 3) + 8 * (r >> 2)) * 32] = f2bf_rh(acc[r]);
        }
        __syncthreads();

        // ---- Phase B: k-split s = 8wu..8wu+7, both i-tiles ----
        // A-frag row ln -> T row (ln&7); rows 8-15 broadcast-duplicate 0-7.
        f32x4 acc0 = {}, acc1 = {};
        const int lg = l >> 4;
        const int ln = l & 15;
        #pragma unroll
        for (int si = 0; si < 8; ++si) {
            const int s = 8 * wu + si;
            const bf16x8 af =
                *(const bf16x8*)(T_lds + (ln & 7) * 1032 + s * 32 + 8 * lg);
            const bf16x8* wrow = (const bf16x8*)(Wf + (size_t)(s * 2) * 512);
            const bf16x8 b0 = wrow[l];        // L2-hot, 16B/lane coalesced
            const bf16x8 b1 = wrow[64 + l];
            acc0 = __builtin_amdgcn_mfma_f32_16x16x32_bf16(af, b0, acc0, 0, 0, 0);
            acc1 = __builtin_amdgcn_mfma_f32_16x16x32_bf16(af, b1, acc1, 0, 0, 0);
        }
        __syncthreads();                  // T reads done; reuse T_lds as f32 red

        float* red = (float*)T_lds;       // 4 waves * 2 tiles * 256 f32 = 8 KB
        {
            f32x4* rp = (f32x4*)(red + wu * 512);
            rp[l]      = acc0;            // [w][t=0][l][r]
            rp[64 + l] = acc1;            // [w][t=1][l][r]
        }
        __syncthreads();

        // 256 outputs: tid -> (bv = tid>>5, i = tid&31).
        {
            const int bv  = tid >> 5;
            const int i   = tid & 31;
            const int t   = i >> 4;
            const int col = i & 15;
            const int lgi = bv >> 2;
            const int r   = bv & 3;
            const int li  = lgi * 16 + col;
            const int o   = t * 256 + li * 4 + r;
            float sum = red[o] + red[512 + o] + red[1024 + o] + red[1536 + o];
            sum += bias[i];
            out[(size_t)(m0 + bv) * 32 + i] = sum > 0.f ? sum : 0.f;
        }
        // next iteration's first LDS write (pack->ckb) is fenced by the
        // pre-phase-A barrier; red reads here precede it on every wave.
    }
}

extern "C" void kernel_launch(void* const* d_in, const int* in_sizes, int n_in,
                              void* d_out, int out_size, void* d_ws, size_t ws_size,
                              hipStream_t stream) {
    const float* sig  = (const float*)d_in[0];
    const int*   pidx = (const int*)d_in[1];
    const float* ck   = (const float*)d_in[2];
    const float* W    = (const float*)d_in[3];
    const float* bias = (const float*)d_in[4];
    float* out = (float*)d_out;
    unsigned short* Wf = (unsigned short*)d_ws;   // 64 KB fragment-ordered W

    prep_kernel<<<128, 256, 0, stream>>>(W, Wf);
    fused_kernel<<<1024, 256, 0, stream>>>(sig, pidx, ck, Wf, bias, out);
}

// Round 12
// 70.074 us; speedup vs baseline: 2.0336x; 2.0336x over previous
//
#include <hip/hip_runtime.h>

// BinaryTreeShConv on MI355X (gfx950).
// out[b,v,i] = relu(bias[i] + sum_{p,c,rn} W[i,c,rn] * K[b,v,p,rn] * sig[b, idx[b,v,p], c])
// B=8 V=4096 P=32 C=32 RN=32 OUT=32, CRN=1024.
//
// R11 = R10 with the scratch-spill bug fixed (rule #20): gather reads rows[]
// with COMPILE-TIME indices + g?hi:lo cndmask (R9 pattern). R10's runtime
// index 8*g forced rows[] to local memory -> 318 MB scratch traffic.
//  - persistent blocks: grid 1024, 4 tiles x 8 bv; tile t+1 ck/idx issued
//    during tile t compute (T14)
//  - prep = Wf pack only; sig gathered f32 + rh at use
//  - per-tile phases = R9: stream -> pack -> A -> B -> reduce

typedef __attribute__((ext_vector_type(8))) short bf16x8;
typedef __attribute__((ext_vector_type(4))) short short4v;
typedef __attribute__((ext_vector_type(16))) float f32x16;
typedef __attribute__((ext_vector_type(4))) float f32x4;

__device__ __forceinline__ unsigned short f2bf_rne(float f) {
    union { float f; unsigned int u; } x;
    x.f = f;
    unsigned int u = x.u;
    return (unsigned short)((u + 0x7fffu + ((u >> 16) & 1u)) >> 16);
}
__device__ __forceinline__ unsigned short f2bf_rh(float f) {  // round-half-up
    union { float f; unsigned int u; } x;
    x.f = f;
    return (unsigned short)((x.u + 0x8000u) >> 16);
}

// Wf[pair=2s+t][lane][j] = bf16(W[i=16t+(lane&15)][crn=32s+8*(lane>>4)+j])
__global__ __launch_bounds__(256) void prep_kernel(
        const float* __restrict__ W, unsigned short* __restrict__ Wf) {
    int tid = blockIdx.x * 256 + threadIdx.x;   // 0..32767
    int j = tid & 7;
    int l = (tid >> 3) & 63;
    int pair = tid >> 9;                        // s*2 + t
    int s = pair >> 1;
    int t = pair & 1;
    int i = 16 * t + (l & 15);
    int crn = 32 * s + 8 * (l >> 4) + j;
    Wf[tid] = f2bf_rne(W[i * 1024 + crn]);
}

__global__ __launch_bounds__(256, 4) void fused_kernel(
        const float* __restrict__ sig, const int* __restrict__ pidx,
        const float* __restrict__ ck, const unsigned short* __restrict__ Wf,
        const float* __restrict__ bias, float* __restrict__ out) {
    __shared__ __align__(16) unsigned short ckb[8 * 1024];   // 16,384 B [bv][p][rn]
    __shared__ __align__(16) unsigned short T_lds[8 * 1032]; // 16,512 B
    const int tid = threadIdx.x;
    const int l = tid & 63;
    const int g = l >> 5;
    const int cc = l & 31;
    const int wu = __builtin_amdgcn_readfirstlane(tid >> 6);  // wave 0..3 (SGPR)
    const int base_m = blockIdx.x * 32;       // 32 bv per block, same b
    const float* sgb = sig + (size_t)(base_m >> 12) * (4096 * 32);
    const f32x4* ckv = (const f32x4*)(ck + (size_t)base_m * 1024);

    // ---- prologue: issue tile-0 ck stream + idx scalar loads ----
    f32x4 st[8];
    #pragma unroll
    for (int i = 0; i < 8; ++i) st[i] = ckv[i * 256 + tid];
    int rows[64];                              // wave-uniform, const-indexed only
    {
        const int* ip = pidx + ((size_t)base_m + 2 * wu) * 32;
        #pragma unroll
        for (int k = 0; k < 64; ++k) rows[k] = ip[k];
    }

    for (int it = 0; it < 4; ++it) {
        const int m0 = base_m + it * 8;

        // ---- gathers (const-index rows + cndmask select; NO runtime index) ----
        unsigned short ga[32];
        #pragma unroll
        for (int q = 0; q < 2; ++q)
            #pragma unroll
            for (int h = 0; h < 2; ++h)
                #pragma unroll
                for (int j = 0; j < 8; ++j) {
                    const int rlo = rows[q * 32 + h * 16 + j];
                    const int rhi = rows[q * 32 + h * 16 + 8 + j];
                    const int row = g ? rhi : rlo;
                    ga[q * 16 + h * 8 + j] = f2bf_rh(sgb[row * 32 + cc]);
                }

        // ---- pack current ck tile into LDS (consumes st) ----
        #pragma unroll
        for (int i = 0; i < 8; ++i) {
            union { f32x4 f; unsigned int u[4]; } x;
            x.f = st[i];
            short4v v = { (short)(x.u[0] >> 16), (short)(x.u[1] >> 16),
                          (short)(x.u[2] >> 16), (short)(x.u[3] >> 16) };
            *(short4v*)(ckb + (i * 256 + tid) * 4) = v;
        }

        // ---- issue NEXT tile's ck stream + idx (hide under phases A/B) ----
        if (it < 3) {
            #pragma unroll
            for (int i = 0; i < 8; ++i)
                st[i] = ckv[(it + 1) * 2048 + i * 256 + tid];
            const int* ip = pidx + ((size_t)m0 + 8 + 2 * wu) * 32;
            #pragma unroll
            for (int k = 0; k < 64; ++k) rows[k] = ip[k];
        }
        __syncthreads();

        // ---- Phase A: stage-A MFMA; wave wu owns bv_local 2wu, 2wu+1 ----
        #pragma unroll
        for (int q = 0; q < 2; ++q) {
            const unsigned short* ct = ckb + (2 * wu + q) * 1024;  // [32p][32rn]
            f32x16 acc = {};
            #pragma unroll
            for (int h = 0; h < 2; ++h) {
                bf16x8 af, bfr;
                #pragma unroll
                for (int j = 0; j < 8; ++j) {
                    const int p = h * 16 + 8 * g + j;
                    af[j]  = (short)ga[q * 16 + h * 8 + j];
                    bfr[j] = (short)ct[p * 32 + cc];
                }
                acc = __builtin_amdgcn_mfma_f32_32x32x16_bf16(af, bfr, acc, 0, 0, 0);
            }
            // D map (verified): col=cc, row=(r&3)+8*(r>>2)+4*g ; T[c][rn] bf16
            unsigned short* trow = T_lds + (2 * wu + q) * 1032 + cc + g * 128;
            #pragma unroll
            for (int r = 0; r < 16; ++r)
                trow[((r & 3) + 8 * (r >> 2)) * 32] = f2bf_rh(acc[r]);
        }
        __syncthreads();

        // ---- Phase B: k-split s = 8wu..8wu+7, both i-tiles ----
        f32x4 acc0 = {}, acc1 = {};
        const int lg = l >> 4;
        const int ln = l & 15;
        #pragma unroll
        for (int si = 0; si < 8; ++si) {
            const int s = 8 * wu + si;
            const bf16x8 af =
                *(const bf16x8*)(T_lds + (ln & 7) * 1032 + s * 32 + 8 * lg);
            const bf16x8* wrow = (const bf16x8*)(Wf + (size_t)(s * 2) * 512);
            const bf16x8 b0 = wrow[l];        // L2-hot, 16B/lane coalesced
            const bf16x8 b1 = wrow[64 + l];
            acc0 = __builtin_amdgcn_mfma_f32_16x16x32_bf16(af, b0, acc0, 0, 0, 0);
            acc1 = __builtin_amdgcn_mfma_f32_16x16x32_bf16(af, b1, acc1, 0, 0, 0);
        }
        __syncthreads();                  // T reads done; reuse T_lds as f32 red

        float* red = (float*)T_lds;       // 4 waves * 2 tiles * 256 f32 = 8 KB
        {
            f32x4* rp = (f32x4*)(red + wu * 512);
            rp[l]      = acc0;            // [w][t=0][l][r]
            rp[64 + l] = acc1;            // [w][t=1][l][r]
        }
        __syncthreads();

        // 256 outputs: tid -> (bv = tid>>5, i = tid&31).
        {
            const int bv  = tid >> 5;
            const int i   = tid & 31;
            const int t   = i >> 4;
            const int col = i & 15;
            const int lgi = bv >> 2;
            const int r   = bv & 3;
            const int li  = lgi * 16 + col;
            const int o   = t * 256 + li * 4 + r;
            float sum = red[o] + red[512 + o] + red[1024 + o] + red[1536 + o];
            sum += bias[i];
            out[(size_t)(m0 + bv) * 32 + i] = sum > 0.f ? sum : 0.f;
        }
    }
}

extern "C" void kernel_launch(void* const* d_in, const int* in_sizes, int n_in,
                              void* d_out, int out_size, void* d_ws, size_t ws_size,
                              hipStream_t stream) {
    const float* sig  = (const float*)d_in[0];
    const int*   pidx = (const int*)d_in[1];
    const float* ck   = (const float*)d_in[2];
    const float* W    = (const float*)d_in[3];
    const float* bias = (const float*)d_in[4];
    float* out = (float*)d_out;
    unsigned short* Wf = (unsigned short*)d_ws;   // 64 KB fragment-ordered W

    prep_kernel<<<128, 256, 0, stream>>>(W, Wf);
    fused_kernel<<<1024, 256, 0, stream>>>(sig, pidx, ck, Wf, bias, out);
}

// Round 13
// 40.781 us; speedup vs baseline: 3.4943x; 1.7183x over previous
//
#include <hip/hip_runtime.h>

// BinaryTreeShConv on MI355X (gfx950).
// out[b,v,i] = relu(bias[i] + sum_{p,c,rn} W[i,c,rn] * K[b,v,p,rn] * sig[b, idx[b,v,p], c])
// B=8 V=4096 P=32 C=32 RN=32 OUT=32, CRN=1024.
//
// R12: R9 structure (best, 38.8) with ckb LDS staging removed.
//  - ck B-fragment loaded DIRECTLY via strided hi-ushort (P2-probe pattern,
//    proven 6.9 TB/s line-rate standalone). No ckb tile, no pack, 1 fewer
//    barrier. LDS 33 -> 16.5 KB.
//  - __launch_bounds__(256,5): 5 blocks/CU (62.5% occ cap), VGPR cap 102.
//  - phase 0 stays pure-load: sa/kb for BOTH q issued back-to-back,
//    all const-indexed (rule #20).
//  - prep (Wf pack + sigbf) and phases A/B/reduce/epilogue byte-identical
//    to R9. Numerics identical: absmax 0.25 expected.

typedef __attribute__((ext_vector_type(8))) short bf16x8;
typedef __attribute__((ext_vector_type(16))) float f32x16;
typedef __attribute__((ext_vector_type(4))) float f32x4;

__device__ __forceinline__ unsigned short f2bf_rne(float f) {
    union { float f; unsigned int u; } x;
    x.f = f;
    unsigned int u = x.u;
    return (unsigned short)((u + 0x7fffu + ((u >> 16) & 1u)) >> 16);
}
__device__ __forceinline__ unsigned short f2bf_rh(float f) {  // round-half-up
    union { float f; unsigned int u; } x;
    x.f = f;
    return (unsigned short)((x.u + 0x8000u) >> 16);
}

// Wf[pair=2s+t][lane][j] = bf16(W[i=16t+(lane&15)][crn=32s+8*(lane>>4)+j])
// plus sig f32 -> bf16 (RNE), 8 elements/thread.
__global__ __launch_bounds__(256) void prep_kernel(
        const float* __restrict__ W, const float* __restrict__ sig,
        unsigned short* __restrict__ Wf, unsigned short* __restrict__ sigbf) {
    int tid = blockIdx.x * 256 + threadIdx.x;
    if (tid < 32768) {
        int j = tid & 7;
        int l = (tid >> 3) & 63;
        int pair = tid >> 9;                    // s*2 + t
        int s = pair >> 1;
        int t = pair & 1;
        int i = 16 * t + (l & 15);
        int crn = 32 * s + 8 * (l >> 4) + j;
        Wf[tid] = f2bf_rne(W[i * 1024 + crn]);
    } else {
        int e = (tid - 32768) * 8;              // sig has 1,048,576 elements
        if (e < 8 * 4096 * 32) {
            f32x4 a = *(const f32x4*)(sig + e);
            f32x4 b = *(const f32x4*)(sig + e + 4);
            bf16x8 v;
            v[0] = (short)f2bf_rne(a[0]); v[1] = (short)f2bf_rne(a[1]);
            v[2] = (short)f2bf_rne(a[2]); v[3] = (short)f2bf_rne(a[3]);
            v[4] = (short)f2bf_rne(b[0]); v[5] = (short)f2bf_rne(b[1]);
            v[6] = (short)f2bf_rne(b[2]); v[7] = (short)f2bf_rne(b[3]);
            *(bf16x8*)(sigbf + e) = v;
        }
    }
}

__global__ __launch_bounds__(256, 5) void fused_kernel(
        const unsigned short* __restrict__ sigbf, const int* __restrict__ pidx,
        const float* __restrict__ ck, const unsigned short* __restrict__ Wf,
        const float* __restrict__ bias, float* __restrict__ out) {
    __shared__ __align__(16) unsigned short T_lds[8 * 1032];  // 16,512 B only
    const int tid = threadIdx.x;
    const int l = tid & 63;
    const int g = l >> 5;
    const int cc = l & 31;
    const int wu = __builtin_amdgcn_readfirstlane(tid >> 6);  // wave 0..3 (SGPR)
    const int m0 = blockIdx.x * 8;   // 8 bv per block (same b)
    const int b = m0 >> 12;
    const unsigned short* sgb = sigbf + (size_t)b * (4096 * 32);
    const unsigned short* ckh = (const unsigned short*)ck;   // [2e+1] = bf16-trunc

    // ---- idx for this wave's 2 bv: wave-uniform scalar loads ----
    int rows[64];
    {
        const int* ip = pidx + ((size_t)m0 + 2 * wu) * 32;
        #pragma unroll
        for (int k = 0; k < 64; ++k) rows[k] = ip[k];
    }

    // ======== Phase 0: pure loads — all sa/kb for both q, back-to-back ======
    unsigned short sa[2][16];   // gathers (bf16, 2/VGPR packed)
    unsigned short kb[2][16];   // ck hi-ushort strided (P2 pattern)
    #pragma unroll
    for (int q = 0; q < 2; ++q) {
        const size_t kh = ((size_t)(m0 + 2 * wu + q) * 1024) * 2 + 1;
        #pragma unroll
        for (int h = 0; h < 2; ++h) {
            #pragma unroll
            for (int j = 0; j < 8; ++j) {
                const int rlo = rows[q * 32 + h * 16 + j];
                const int rhi = rows[q * 32 + h * 16 + 8 + j];
                const int row = g ? rhi : rlo;               // lane's p = h16+8g+j
                sa[q][h * 8 + j] = sgb[row * 32 + cc];
                kb[q][h * 8 + j] =
                    ckh[kh + (size_t)((h * 16 + 8 * g + j) * 32 + cc) * 2];
            }
        }
    }

    // ======== Phase A: stage-A MFMA; wave wu owns bv_local 2wu, 2wu+1 ======
    #pragma unroll
    for (int q = 0; q < 2; ++q) {
        f32x16 acc = {};
        #pragma unroll
        for (int h = 0; h < 2; ++h) {
            bf16x8 af, bfr;
            #pragma unroll
            for (int j = 0; j < 8; ++j) {
                af[j]  = (short)sa[q][h * 8 + j];
                bfr[j] = (short)kb[q][h * 8 + j];
            }
            acc = __builtin_amdgcn_mfma_f32_32x32x16_bf16(af, bfr, acc, 0, 0, 0);
        }
        // D map (verified): col=cc, row=(r&3)+8*(r>>2)+4*g ; T[c][rn] bf16
        unsigned short* trow = T_lds + (2 * wu + q) * 1032 + cc + g * 128;
        #pragma unroll
        for (int r = 0; r < 16; ++r)
            trow[((r & 3) + 8 * (r >> 2)) * 32] = f2bf_rh(acc[r]);
    }
    __syncthreads();

    // ======== Phase B: k-split s = 8wu..8wu+7, both i-tiles ======
    // A-frag row ln -> T row (ln&7); rows 8-15 broadcast-duplicate 0-7.
    f32x4 acc0 = {}, acc1 = {};
    const int lg = l >> 4;
    const int ln = l & 15;
    #pragma unroll
    for (int si = 0; si < 8; ++si) {
        const int s = 8 * wu + si;
        const bf16x8 af =
            *(const bf16x8*)(T_lds + (ln & 7) * 1032 + s * 32 + 8 * lg);
        const bf16x8* wrow = (const bf16x8*)(Wf + (size_t)(s * 2) * 512);
        const bf16x8 b0 = wrow[l];        // L2-hot, 16B/lane coalesced
        const bf16x8 b1 = wrow[64 + l];
        acc0 = __builtin_amdgcn_mfma_f32_16x16x32_bf16(af, b0, acc0, 0, 0, 0);
        acc1 = __builtin_amdgcn_mfma_f32_16x16x32_bf16(af, b1, acc1, 0, 0, 0);
    }
    __syncthreads();                      // T reads done; reuse T_lds as f32 red

    float* red = (float*)T_lds;           // 4 waves * 2 tiles * 256 f32 = 8 KB
    {
        f32x4* rp = (f32x4*)(red + wu * 512);
        rp[l]      = acc0;                // [w][t=0][l][r]
        rp[64 + l] = acc1;                // [w][t=1][l][r]
    }
    __syncthreads();

    // 256 outputs: tid -> (bv = tid>>5, i = tid&31).
    {
        const int bv  = tid >> 5;
        const int i   = tid & 31;
        const int t   = i >> 4;
        const int col = i & 15;
        const int lgi = bv >> 2;
        const int r   = bv & 3;
        const int li  = lgi * 16 + col;
        const int o   = t * 256 + li * 4 + r;
        float sum = red[o] + red[512 + o] + red[1024 + o] + red[1536 + o];
        sum += bias[i];
        out[(size_t)(m0 + bv) * 32 + i] = sum > 0.f ? sum : 0.f;
    }
}

extern "C" void kernel_launch(void* const* d_in, const int* in_sizes, int n_in,
                              void* d_out, int out_size, void* d_ws, size_t ws_size,
                              hipStream_t stream) {
    const float* sig  = (const float*)d_in[0];
    const int*   pidx = (const int*)d_in[1];
    const float* ck   = (const float*)d_in[2];
    const float* W    = (const float*)d_in[3];
    const float* bias = (const float*)d_in[4];
    float* out = (float*)d_out;
    unsigned short* Wf    = (unsigned short*)d_ws;       // 64 KB fragment-ordered W
    unsigned short* sigbf = Wf + 32768;                  // 2 MB bf16 signal

    prep_kernel<<<640, 256, 0, stream>>>(W, sig, Wf, sigbf);
    fused_kernel<<<4096, 256, 0, stream>>>(sigbf, pidx, ck, Wf, bias, out);
}

// Round 14
// 40.505 us; speedup vs baseline: 3.5182x; 1.0068x over previous
//
#include <hip/hip_runtime.h>

// BinaryTreeShConv on MI355X (gfx950).
// out[b,v,i] = relu(bias[i] + sum_{p,c,rn} W[i,c,rn] * K[b,v,p,rn] * sig[b, idx[b,v,p], c])
// B=8 V=4096 P=32 C=32 RN=32 OUT=32, CRN=1024.
//
// R13 = R9 (best, 38.8) with two proven deltas:
//  1. prep = Wf pack ONLY (128 blocks). sigbf dropped: gathers read sig f32
//     directly + round-half-up at load (R4/R11 proved numerics + perf).
//  2. idx scalar loads hoisted to top of phase 0 (latency hides under the
//     ck f32x4 issue burst).
// Everything else byte-identical to R9: ckb f32x4->LDS staging, phase A/B,
// k-split reduce, epilogue, grid 4096 x 256, __launch_bounds__(256,4).

typedef __attribute__((ext_vector_type(8))) short bf16x8;
typedef __attribute__((ext_vector_type(4))) short short4v;
typedef __attribute__((ext_vector_type(16))) float f32x16;
typedef __attribute__((ext_vector_type(4))) float f32x4;

__device__ __forceinline__ unsigned short f2bf_rne(float f) {
    union { float f; unsigned int u; } x;
    x.f = f;
    unsigned int u = x.u;
    return (unsigned short)((u + 0x7fffu + ((u >> 16) & 1u)) >> 16);
}
__device__ __forceinline__ unsigned short f2bf_rh(float f) {  // round-half-up
    union { float f; unsigned int u; } x;
    x.f = f;
    return (unsigned short)((x.u + 0x8000u) >> 16);
}

// Wf[pair=2s+t][lane][j] = bf16(W[i=16t+(lane&15)][crn=32s+8*(lane>>4)+j])
__global__ __launch_bounds__(256) void prep_kernel(
        const float* __restrict__ W, unsigned short* __restrict__ Wf) {
    int tid = blockIdx.x * 256 + threadIdx.x;   // 0..32767
    int j = tid & 7;
    int l = (tid >> 3) & 63;
    int pair = tid >> 9;                        // s*2 + t
    int s = pair >> 1;
    int t = pair & 1;
    int i = 16 * t + (l & 15);
    int crn = 32 * s + 8 * (l >> 4) + j;
    Wf[tid] = f2bf_rne(W[i * 1024 + crn]);
}

__global__ __launch_bounds__(256, 4) void fused_kernel(
        const float* __restrict__ sig, const int* __restrict__ pidx,
        const float* __restrict__ ck, const unsigned short* __restrict__ Wf,
        const float* __restrict__ bias, float* __restrict__ out) {
    __shared__ __align__(16) unsigned short ckb[8 * 1024];   // 16,384 B [bv][p][rn]
    __shared__ __align__(16) unsigned short T_lds[8 * 1032]; // 16,512 B
    const int tid = threadIdx.x;
    const int l = tid & 63;
    const int g = l >> 5;
    const int cc = l & 31;
    const int wu = __builtin_amdgcn_readfirstlane(tid >> 6);  // wave 0..3 (SGPR)
    const int m0 = blockIdx.x * 8;   // 8 bv per block (same b)
    const int b = m0 >> 12;
    const float* sgb = sig + (size_t)b * (4096 * 32);

    // ======== Phase 0: pure streaming ========
    // (a) idx FIRST: wave-uniform scalar loads (HBM-cold; latency hides
    //     under the ck issue burst below)
    int rows[64];
    {
        const int* ip = pidx + ((size_t)m0 + 2 * wu) * 32;
        #pragma unroll
        for (int k = 0; k < 64; ++k) rows[k] = ip[k];
    }
    // (b) ck staging: 8 bv x 4 KB = 32 KB, 8 f32x4 per thread, all issued up front
    f32x4 st[8];
    {
        const f32x4* ckv = (const f32x4*)(ck + (size_t)m0 * 1024);
        #pragma unroll
        for (int i = 0; i < 8; ++i) st[i] = ckv[i * 256 + tid];
    }
    // (c) gathers: 32 per lane (2 bv x 16), f32 sig + rh-convert at load;
    //     const-indexed rows + g?hi:lo cndmask (rule #20)
    unsigned short ga[32];
    #pragma unroll
    for (int q = 0; q < 2; ++q) {
        #pragma unroll
        for (int h = 0; h < 2; ++h) {
            #pragma unroll
            for (int j = 0; j < 8; ++j) {
                const int rlo = rows[q * 32 + h * 16 + j];
                const int rhi = rows[q * 32 + h * 16 + 8 + j];
                const int row = g ? rhi : rlo;
                ga[q * 16 + h * 8 + j] = f2bf_rh(sgb[row * 32 + cc]);
            }
        }
    }
    // (d) pack ck staging to bf16 and write LDS (linear, coalesced b64)
    #pragma unroll
    for (int i = 0; i < 8; ++i) {
        union { f32x4 f; unsigned int u[4]; } x;
        x.f = st[i];
        short4v v = { (short)(x.u[0] >> 16), (short)(x.u[1] >> 16),
                      (short)(x.u[2] >> 16), (short)(x.u[3] >> 16) };
        *(short4v*)(ckb + (i * 256 + tid) * 4) = v;
    }
    __syncthreads();

    // ======== Phase A: stage-A MFMA (LDS + regs only) ========
    // wave wu owns bv_local = 2wu, 2wu+1
    #pragma unroll
    for (int q = 0; q < 2; ++q) {
        const unsigned short* ct = ckb + (2 * wu + q) * 1024;   // [32p][32rn]
        f32x16 acc = {};
        #pragma unroll
        for (int h = 0; h < 2; ++h) {
            bf16x8 af, bfr;
            #pragma unroll
            for (int j = 0; j < 8; ++j) {
                const int p = h * 16 + 8 * g + j;
                af[j]  = (short)ga[q * 16 + h * 8 + j];
                bfr[j] = (short)ct[p * 32 + cc];
            }
            acc = __builtin_amdgcn_mfma_f32_32x32x16_bf16(af, bfr, acc, 0, 0, 0);
        }
        // D map (verified): col=cc, row=(r&3)+8*(r>>2)+4*g ; T[c][rn] bf16
        unsigned short* trow = T_lds + (2 * wu + q) * 1032 + cc + g * 128;
        #pragma unroll
        for (int r = 0; r < 16; ++r)
            trow[((r & 3) + 8 * (r >> 2)) * 32] = f2bf_rh(acc[r]);
    }
    __syncthreads();

    // ======== Phase B: stage B, k-split s = 8wu..8wu+7, both i-tiles ========
    // A-frag row ln -> T row (ln&7); rows 8-15 broadcast-duplicate 0-7.
    f32x4 acc0 = {}, acc1 = {};
    const int lg = l >> 4;
    const int ln = l & 15;
    #pragma unroll
    for (int si = 0; si < 8; ++si) {
        const int s = 8 * wu + si;
        const bf16x8 af = *(const bf16x8*)(T_lds + (ln & 7) * 1032 + s * 32 + 8 * lg);
        const bf16x8* wrow = (const bf16x8*)(Wf + (size_t)(s * 2) * 512);
        const bf16x8 b0 = wrow[l];        // pair 2s+0, coalesced 16B/lane, L2-hot
        const bf16x8 b1 = wrow[64 + l];   // pair 2s+1
        acc0 = __builtin_amdgcn_mfma_f32_16x16x32_bf16(af, b0, acc0, 0, 0, 0);
        acc1 = __builtin_amdgcn_mfma_f32_16x16x32_bf16(af, b1, acc1, 0, 0, 0);
    }
    __syncthreads();                      // T reads done; reuse T_lds as f32 red

    float* red = (float*)T_lds;           // 4 waves * 2 tiles * 256 f32 = 8 KB
    {
        f32x4* rp = (f32x4*)(red + wu * 512);
        rp[l]      = acc0;                // [w][t=0][l][r]
        rp[64 + l] = acc1;                // [w][t=1][l][r]
    }
    __syncthreads();

    // 256 outputs: thread tid -> (bv = tid>>5, i = tid&31).
    {
        const int bv  = tid >> 5;
        const int i   = tid & 31;
        const int t   = i >> 4;
        const int col = i & 15;
        const int lgi = bv >> 2;          // 0..1
        const int r   = bv & 3;
        const int li  = lgi * 16 + col;
        const int o   = t * 256 + li * 4 + r;
        float sum = red[o] + red[512 + o] + red[1024 + o] + red[1536 + o];
        sum += bias[i];
        out[(size_t)(m0 + bv) * 32 + i] = sum > 0.f ? sum : 0.f;
    }
}

extern "C" void kernel_launch(void* const* d_in, const int* in_sizes, int n_in,
                              void* d_out, int out_size, void* d_ws, size_t ws_size,
                              hipStream_t stream) {
    const float* sig  = (const float*)d_in[0];
    const int*   pidx = (const int*)d_in[1];
    const float* ck   = (const float*)d_in[2];
    const float* W    = (const float*)d_in[3];
    const float* bias = (const float*)d_in[4];
    float* out = (float*)d_out;
    unsigned short* Wf = (unsigned short*)d_ws;   // 64 KB fragment-ordered W

    prep_kernel<<<128, 256, 0, stream>>>(W, Wf);
    fused_kernel<<<4096, 256, 0, stream>>>(sig, pidx, ck, Wf, bias, out);
}

// Round 15
// 37.005 us; speedup vs baseline: 3.8509x; 1.0946x over previous
//
#include <hip/hip_runtime.h>

// BinaryTreeShConv on MI355X (gfx950).
// out[b,v,i] = relu(bias[i] + sum_{p,c,rn} W[i,c,rn] * K[b,v,p,rn] * sig[b, idx[b,v,p], c])
// B=8 V=4096 P=32 C=32 RN=32 OUT=32, CRN=1024.
//
// R14: R9 algorithm/numerics, occupancy-doubled geometry.
//  - 512-thread blocks (8 waves), 8 bv/block: wave w owns bv w in stage A
//    (st[4]=16 VGPR, ga[16] u16, rows[32]->SGPR), k-split 4 s/wave in stage B.
//  - __launch_bounds__(512,8): VGPR cap 64 -> 32 waves/CU (was 16, LDS-capped
//    at 4 blocks either way). Same LDS 32.9 KB, same barriers, same per-bv code.
//  - prep = R9's (Wf pack + sigbf): R13 proved dropping sigbf regresses.
// Numerics identical to R9 (absmax 0.25).

typedef __attribute__((ext_vector_type(8))) short bf16x8;
typedef __attribute__((ext_vector_type(4))) short short4v;
typedef __attribute__((ext_vector_type(16))) float f32x16;
typedef __attribute__((ext_vector_type(4))) float f32x4;

__device__ __forceinline__ unsigned short f2bf_rne(float f) {
    union { float f; unsigned int u; } x;
    x.f = f;
    unsigned int u = x.u;
    return (unsigned short)((u + 0x7fffu + ((u >> 16) & 1u)) >> 16);
}
__device__ __forceinline__ unsigned short f2bf_rh(float f) {  // round-half-up
    union { float f; unsigned int u; } x;
    x.f = f;
    return (unsigned short)((x.u + 0x8000u) >> 16);
}

// Wf[pair=2s+t][lane][j] = bf16(W[i=16t+(lane&15)][crn=32s+8*(lane>>4)+j])
// plus sig f32 -> bf16 (RNE), 8 elements/thread.
__global__ __launch_bounds__(256) void prep_kernel(
        const float* __restrict__ W, const float* __restrict__ sig,
        unsigned short* __restrict__ Wf, unsigned short* __restrict__ sigbf) {
    int tid = blockIdx.x * 256 + threadIdx.x;
    if (tid < 32768) {
        int j = tid & 7;
        int l = (tid >> 3) & 63;
        int pair = tid >> 9;                    // s*2 + t
        int s = pair >> 1;
        int t = pair & 1;
        int i = 16 * t + (l & 15);
        int crn = 32 * s + 8 * (l >> 4) + j;
        Wf[tid] = f2bf_rne(W[i * 1024 + crn]);
    } else {
        int e = (tid - 32768) * 8;              // sig has 1,048,576 elements
        if (e < 8 * 4096 * 32) {
            f32x4 a = *(const f32x4*)(sig + e);
            f32x4 b = *(const f32x4*)(sig + e + 4);
            bf16x8 v;
            v[0] = (short)f2bf_rne(a[0]); v[1] = (short)f2bf_rne(a[1]);
            v[2] = (short)f2bf_rne(a[2]); v[3] = (short)f2bf_rne(a[3]);
            v[4] = (short)f2bf_rne(b[0]); v[5] = (short)f2bf_rne(b[1]);
            v[6] = (short)f2bf_rne(b[2]); v[7] = (short)f2bf_rne(b[3]);
            *(bf16x8*)(sigbf + e) = v;
        }
    }
}

__global__ __launch_bounds__(512, 8) void fused_kernel(
        const unsigned short* __restrict__ sigbf, const int* __restrict__ pidx,
        const float* __restrict__ ck, const unsigned short* __restrict__ Wf,
        const float* __restrict__ bias, float* __restrict__ out) {
    __shared__ __align__(16) unsigned short ckb[8 * 1024];   // 16,384 B [bv][p][rn]
    __shared__ __align__(16) unsigned short T_lds[8 * 1032]; // 16,512 B
    const int tid = threadIdx.x;
    const int l = tid & 63;
    const int g = l >> 5;
    const int cc = l & 31;
    const int wu = __builtin_amdgcn_readfirstlane(tid >> 6);  // wave 0..7 (SGPR)
    const int m0 = blockIdx.x * 8;   // 8 bv per block (same b)
    const int b = m0 >> 12;
    const unsigned short* sgb = sigbf + (size_t)b * (4096 * 32);

    // ======== Phase 0: pure streaming; wave wu owns bv wu ========
    // (a) idx: wave-uniform scalar loads (32 ints -> SGPRs)
    int rows[32];
    {
        const int* ip = pidx + (size_t)(m0 + wu) * 32;
        #pragma unroll
        for (int k = 0; k < 32; ++k) rows[k] = ip[k];
    }
    // (b) ck staging for bv wu: 4 KB = 4 f32x4 per lane, issued up front
    f32x4 st[4];
    {
        const f32x4* ckv = (const f32x4*)(ck + (size_t)(m0 + wu) * 1024);
        #pragma unroll
        for (int i = 0; i < 4; ++i) st[i] = ckv[i * 64 + l];
    }
    // (c) gathers: 16 per lane (1 bv), u16 from sigbf; const-indexed rows
    //     + g?hi:lo cndmask (rule #20)
    unsigned short ga[16];
    #pragma unroll
    for (int h = 0; h < 2; ++h) {
        #pragma unroll
        for (int j = 0; j < 8; ++j) {
            const int rlo = rows[h * 16 + j];
            const int rhi = rows[h * 16 + 8 + j];
            const int row = g ? rhi : rlo;
            ga[h * 8 + j] = sgb[row * 32 + cc];
        }
    }
    // (d) pack ck staging to bf16 -> LDS (linear, coalesced b64)
    #pragma unroll
    for (int i = 0; i < 4; ++i) {
        union { f32x4 f; unsigned int u[4]; } x;
        x.f = st[i];
        short4v v = { (short)(x.u[0] >> 16), (short)(x.u[1] >> 16),
                      (short)(x.u[2] >> 16), (short)(x.u[3] >> 16) };
        *(short4v*)(ckb + wu * 1024 + (i * 64 + l) * 4) = v;
    }
    __syncthreads();

    // ======== Phase A: stage-A MFMA; wave wu computes T for bv wu ========
    {
        const unsigned short* ct = ckb + wu * 1024;   // [32p][32rn]
        f32x16 acc = {};
        #pragma unroll
        for (int h = 0; h < 2; ++h) {
            bf16x8 af, bfr;
            #pragma unroll
            for (int j = 0; j < 8; ++j) {
                const int p = h * 16 + 8 * g + j;
                af[j]  = (short)ga[h * 8 + j];
                bfr[j] = (short)ct[p * 32 + cc];
            }
            acc = __builtin_amdgcn_mfma_f32_32x32x16_bf16(af, bfr, acc, 0, 0, 0);
        }
        // D map (verified): col=cc, row=(r&3)+8*(r>>2)+4*g ; T[c][rn] bf16
        unsigned short* trow = T_lds + wu * 1032 + cc + g * 128;
        #pragma unroll
        for (int r = 0; r < 16; ++r)
            trow[((r & 3) + 8 * (r >> 2)) * 32] = f2bf_rh(acc[r]);
    }
    __syncthreads();

    // ======== Phase B: k-split s = 4wu..4wu+3, both i-tiles ========
    // A-frag row ln -> T row (ln&7); rows 8-15 broadcast-duplicate 0-7.
    f32x4 acc0 = {}, acc1 = {};
    const int lg = l >> 4;
    const int ln = l & 15;
    #pragma unroll
    for (int si = 0; si < 4; ++si) {
        const int s = 4 * wu + si;
        const bf16x8 af =
            *(const bf16x8*)(T_lds + (ln & 7) * 1032 + s * 32 + 8 * lg);
        const bf16x8* wrow = (const bf16x8*)(Wf + (size_t)(s * 2) * 512);
        const bf16x8 b0 = wrow[l];        // pair 2s+0, 16B/lane coalesced, L2-hot
        const bf16x8 b1 = wrow[64 + l];   // pair 2s+1
        acc0 = __builtin_amdgcn_mfma_f32_16x16x32_bf16(af, b0, acc0, 0, 0, 0);
        acc1 = __builtin_amdgcn_mfma_f32_16x16x32_bf16(af, b1, acc1, 0, 0, 0);
    }
    __syncthreads();                      // T reads done; reuse T_lds as f32 red

    float* red = (float*)T_lds;           // 8 waves * 2 tiles * 256 f32 = 16 KB
    {
        f32x4* rp = (f32x4*)(red + wu * 512);
        rp[l]      = acc0;                // [w][t=0][l][r]
        rp[64 + l] = acc1;                // [w][t=1][l][r]
    }
    __syncthreads();

    // 256 outputs: threads 0-255 -> (bv = tid>>5, i = tid&31); 8-way k-sum.
    if (tid < 256) {
        const int bv  = tid >> 5;
        const int i   = tid & 31;
        const int t   = i >> 4;
        const int col = i & 15;
        const int lgi = bv >> 2;          // 0..1
        const int r   = bv & 3;
        const int li  = lgi * 16 + col;
        const int o   = t * 256 + li * 4 + r;
        float sum = 0.f;
        #pragma unroll
        for (int w2 = 0; w2 < 8; ++w2) sum += red[w2 * 512 + o];
        sum += bias[i];
        out[(size_t)(m0 + bv) * 32 + i] = sum > 0.f ? sum : 0.f;
    }
}

extern "C" void kernel_launch(void* const* d_in, const int* in_sizes, int n_in,
                              void* d_out, int out_size, void* d_ws, size_t ws_size,
                              hipStream_t stream) {
    const float* sig  = (const float*)d_in[0];
    const int*   pidx = (const int*)d_in[1];
    const float* ck   = (const float*)d_in[2];
    const float* W    = (const float*)d_in[3];
    const float* bias = (const float*)d_in[4];
    float* out = (float*)d_out;
    unsigned short* Wf    = (unsigned short*)d_ws;       // 64 KB fragment-ordered W
    unsigned short* sigbf = Wf + 32768;                  // 2 MB bf16 signal

    prep_kernel<<<640, 256, 0, stream>>>(W, sig, Wf, sigbf);
    fused_kernel<<<4096, 512, 0, stream>>>(sigbf, pidx, ck, Wf, bias, out);
}

// Round 16
// 36.469 us; speedup vs baseline: 3.9075x; 1.0147x over previous
//
#include <hip/hip_runtime.h>

// BinaryTreeShConv on MI355X (gfx950).
// out[b,v,i] = relu(bias[i] + sum_{p,c,rn} W[i,c,rn] * K[b,v,p,rn] * sig[b, idx[b,v,p], c])
// B=8 V=4096 P=32 C=32 RN=32 OUT=32, CRN=1024.
//
// R15 = R14 (best, 37.0) with barrier count 4 -> 2:
//  - barrier after ckb-write REMOVED: wave wu writes only ckb[wu] and phase A
//    reads only ckb[wu] (intra-wave RAW via in-order DS ops; no cross-wave dep)
//  - reduction buffer moved T_lds -> ckb (dead after phase A; wave overwrites
//    only its own region): removes the barrier between phase-B T reads and
//    red writes.
// Remaining barriers: (1) T ready, (2) red ready. Geometry/numerics == R14:
// 512 thr / 8 waves / 8 bv, wave owns 1 bv in A, k-split 4 s/wave in B,
// __launch_bounds__(512,8), prep = Wf pack + sigbf. absmax 0.25 expected.

typedef __attribute__((ext_vector_type(8))) short bf16x8;
typedef __attribute__((ext_vector_type(4))) short short4v;
typedef __attribute__((ext_vector_type(16))) float f32x16;
typedef __attribute__((ext_vector_type(4))) float f32x4;

__device__ __forceinline__ unsigned short f2bf_rne(float f) {
    union { float f; unsigned int u; } x;
    x.f = f;
    unsigned int u = x.u;
    return (unsigned short)((u + 0x7fffu + ((u >> 16) & 1u)) >> 16);
}
__device__ __forceinline__ unsigned short f2bf_rh(float f) {  // round-half-up
    union { float f; unsigned int u; } x;
    x.f = f;
    return (unsigned short)((x.u + 0x8000u) >> 16);
}

// Wf[pair=2s+t][lane][j] = bf16(W[i=16t+(lane&15)][crn=32s+8*(lane>>4)+j])
// plus sig f32 -> bf16 (RNE), 8 elements/thread.
__global__ __launch_bounds__(256) void prep_kernel(
        const float* __restrict__ W, const float* __restrict__ sig,
        unsigned short* __restrict__ Wf, unsigned short* __restrict__ sigbf) {
    int tid = blockIdx.x * 256 + threadIdx.x;
    if (tid < 32768) {
        int j = tid & 7;
        int l = (tid >> 3) & 63;
        int pair = tid >> 9;                    // s*2 + t
        int s = pair >> 1;
        int t = pair & 1;
        int i = 16 * t + (l & 15);
        int crn = 32 * s + 8 * (l >> 4) + j;
        Wf[tid] = f2bf_rne(W[i * 1024 + crn]);
    } else {
        int e = (tid - 32768) * 8;              // sig has 1,048,576 elements
        if (e < 8 * 4096 * 32) {
            f32x4 a = *(const f32x4*)(sig + e);
            f32x4 b = *(const f32x4*)(sig + e + 4);
            bf16x8 v;
            v[0] = (short)f2bf_rne(a[0]); v[1] = (short)f2bf_rne(a[1]);
            v[2] = (short)f2bf_rne(a[2]); v[3] = (short)f2bf_rne(a[3]);
            v[4] = (short)f2bf_rne(b[0]); v[5] = (short)f2bf_rne(b[1]);
            v[6] = (short)f2bf_rne(b[2]); v[7] = (short)f2bf_rne(b[3]);
            *(bf16x8*)(sigbf + e) = v;
        }
    }
}

__global__ __launch_bounds__(512, 8) void fused_kernel(
        const unsigned short* __restrict__ sigbf, const int* __restrict__ pidx,
        const float* __restrict__ ck, const unsigned short* __restrict__ Wf,
        const float* __restrict__ bias, float* __restrict__ out) {
    __shared__ __align__(16) unsigned short ckb[8 * 1024];   // 16,384 B; ck tiles,
                                                             // then f32 red buffer
    __shared__ __align__(16) unsigned short T_lds[8 * 1032]; // 16,512 B
    const int tid = threadIdx.x;
    const int l = tid & 63;
    const int g = l >> 5;
    const int cc = l & 31;
    const int wu = __builtin_amdgcn_readfirstlane(tid >> 6);  // wave 0..7 (SGPR)
    const int m0 = blockIdx.x * 8;   // 8 bv per block (same b)
    const int b = m0 >> 12;
    const unsigned short* sgb = sigbf + (size_t)b * (4096 * 32);

    // ======== Phase 0: pure streaming; wave wu owns bv wu ========
    // (a) idx: wave-uniform scalar loads (32 ints -> SGPRs)
    int rows[32];
    {
        const int* ip = pidx + (size_t)(m0 + wu) * 32;
        #pragma unroll
        for (int k = 0; k < 32; ++k) rows[k] = ip[k];
    }
    // (b) ck staging for bv wu: 4 KB = 4 f32x4 per lane, issued up front
    f32x4 st[4];
    {
        const f32x4* ckv = (const f32x4*)(ck + (size_t)(m0 + wu) * 1024);
        #pragma unroll
        for (int i = 0; i < 4; ++i) st[i] = ckv[i * 64 + l];
    }
    // (c) gathers: 16 per lane (1 bv), u16 from sigbf; const-indexed rows
    //     + g?hi:lo cndmask (rule #20)
    unsigned short ga[16];
    #pragma unroll
    for (int h = 0; h < 2; ++h) {
        #pragma unroll
        for (int j = 0; j < 8; ++j) {
            const int rlo = rows[h * 16 + j];
            const int rhi = rows[h * 16 + 8 + j];
            const int row = g ? rhi : rlo;
            ga[h * 8 + j] = sgb[row * 32 + cc];
        }
    }
    // (d) pack ck staging to bf16 -> LDS (linear, coalesced b64).
    //     NO barrier: wave wu writes only ckb[wu], and phase A below reads
    //     only ckb[wu] — intra-wave RAW, in-order DS ops + lgkmcnt suffice.
    #pragma unroll
    for (int i = 0; i < 4; ++i) {
        union { f32x4 f; unsigned int u[4]; } x;
        x.f = st[i];
        short4v v = { (short)(x.u[0] >> 16), (short)(x.u[1] >> 16),
                      (short)(x.u[2] >> 16), (short)(x.u[3] >> 16) };
        *(short4v*)(ckb + wu * 1024 + (i * 64 + l) * 4) = v;
    }

    // ======== Phase A: stage-A MFMA; wave wu computes T for bv wu ========
    {
        const unsigned short* ct = ckb + wu * 1024;   // [32p][32rn], own region
        f32x16 acc = {};
        #pragma unroll
        for (int h = 0; h < 2; ++h) {
            bf16x8 af, bfr;
            #pragma unroll
            for (int j = 0; j < 8; ++j) {
                const int p = h * 16 + 8 * g + j;
                af[j]  = (short)ga[h * 8 + j];
                bfr[j] = (short)ct[p * 32 + cc];
            }
            acc = __builtin_amdgcn_mfma_f32_32x32x16_bf16(af, bfr, acc, 0, 0, 0);
        }
        // D map (verified): col=cc, row=(r&3)+8*(r>>2)+4*g ; T[c][rn] bf16
        unsigned short* trow = T_lds + wu * 1032 + cc + g * 128;
        #pragma unroll
        for (int r = 0; r < 16; ++r)
            trow[((r & 3) + 8 * (r >> 2)) * 32] = f2bf_rh(acc[r]);
    }
    __syncthreads();   // barrier 1: all T rows visible to all waves

    // ======== Phase B: k-split s = 4wu..4wu+3, both i-tiles ========
    // A-frag row ln -> T row (ln&7); rows 8-15 broadcast-duplicate 0-7.
    f32x4 acc0 = {}, acc1 = {};
    const int lg = l >> 4;
    const int ln = l & 15;
    #pragma unroll
    for (int si = 0; si < 4; ++si) {
        const int s = 4 * wu + si;
        const bf16x8 af =
            *(const bf16x8*)(T_lds + (ln & 7) * 1032 + s * 32 + 8 * lg);
        const bf16x8* wrow = (const bf16x8*)(Wf + (size_t)(s * 2) * 512);
        const bf16x8 b0 = wrow[l];        // pair 2s+0, 16B/lane coalesced, L2-hot
        const bf16x8 b1 = wrow[64 + l];   // pair 2s+1
        acc0 = __builtin_amdgcn_mfma_f32_16x16x32_bf16(af, b0, acc0, 0, 0, 0);
        acc1 = __builtin_amdgcn_mfma_f32_16x16x32_bf16(af, b1, acc1, 0, 0, 0);
    }

    // red buffer = ckb (dead after phase A; wave wu overwrites only the
    // region it alone read) — no barrier between T reads and these writes.
    float* red = (float*)ckb;             // 8 waves * 512 f32 = 16,384 B exact
    {
        f32x4* rp = (f32x4*)(red + wu * 512);
        rp[l]      = acc0;                // [w][t=0][l][r]
        rp[64 + l] = acc1;                // [w][t=1][l][r]
    }
    __syncthreads();   // barrier 2: red complete

    // 256 outputs: threads 0-255 -> (bv = tid>>5, i = tid&31); 8-way k-sum.
    if (tid < 256) {
        const int bv  = tid >> 5;
        const int i   = tid & 31;
        const int t   = i >> 4;
        const int col = i & 15;
        const int lgi = bv >> 2;          // 0..1
        const int r   = bv & 3;
        const int li  = lgi * 16 + col;
        const int o   = t * 256 + li * 4 + r;
        float sum = 0.f;
        #pragma unroll
        for (int w2 = 0; w2 < 8; ++w2) sum += red[w2 * 512 + o];
        sum += bias[i];
        out[(size_t)(m0 + bv) * 32 + i] = sum > 0.f ? sum : 0.f;
    }
}

extern "C" void kernel_launch(void* const* d_in, const int* in_sizes, int n_in,
                              void* d_out, int out_size, void* d_ws, size_t ws_size,
                              hipStream_t stream) {
    const float* sig  = (const float*)d_in[0];
    const int*   pidx = (const int*)d_in[1];
    const float* ck   = (const float*)d_in[2];
    const float* W    = (const float*)d_in[3];
    const float* bias = (const float*)d_in[4];
    float* out = (float*)d_out;
    unsigned short* Wf    = (unsigned short*)d_ws;       // 64 KB fragment-ordered W
    unsigned short* sigbf = Wf + 32768;                  // 2 MB bf16 signal

    prep_kernel<<<640, 256, 0, stream>>>(W, sig, Wf, sigbf);
    fused_kernel<<<4096, 512, 0, stream>>>(sigbf, pidx, ck, Wf, bias, out);
}